// Round 2
// baseline (1369.816 us; speedup 1.0000x reference)
//
#include <hip/hip_runtime.h>
#include <cstddef>

// Problem constants (B=16, S=1024, D=256, H=8 -> H2=4 heads/branch, DEPTH=32, DH=128)
static constexpr int BB = 16, SS = 1024, DD = 256;
static constexpr size_t OUTW = (size_t)BB * SS * DD;          // 4,194,304 floats: start of attn_w in d_out
#define SCALE 0.17677669529663687f                             // 1/sqrt(32)

// ---------------------------------------------------------------------------
// pack: Wcat[g] = [W_dist | W_adj] (256x256) for g in {q,k,v}; bcat likewise
// ---------------------------------------------------------------------------
__global__ __launch_bounds__(256) void pack_kernel(
    const float* __restrict__ Wqd, const float* __restrict__ Wqa,
    const float* __restrict__ Wkd, const float* __restrict__ Wka,
    const float* __restrict__ Wvd, const float* __restrict__ Wva,
    const float* __restrict__ bqd, const float* __restrict__ bqa,
    const float* __restrict__ bkd, const float* __restrict__ bka,
    const float* __restrict__ bvd, const float* __restrict__ bva,
    float* __restrict__ Wcat, float* __restrict__ bcat)
{
  int i = blockIdx.x * 256 + threadIdx.x;
  if (i < 3 * 256 * 256) {
    int g = i >> 16, r = (i >> 8) & 255, n = i & 255;
    const float* W0 = (g == 0) ? Wqd : (g == 1) ? Wkd : Wvd;
    const float* W1 = (g == 0) ? Wqa : (g == 1) ? Wka : Wva;
    Wcat[i] = (n < 128) ? W0[r * 128 + n] : W1[r * 128 + (n - 128)];
  } else {
    int j = i - 3 * 256 * 256;
    if (j < 3 * 256) {
      int g = j >> 8, n = j & 255;
      const float* b0 = (g == 0) ? bqd : (g == 1) ? bkd : bvd;
      const float* b1 = (g == 0) ? bqa : (g == 1) ? bka : bva;
      bcat[j] = (n < 128) ? b0[n] : b1[n - 128];
    }
  }
}

// ---------------------------------------------------------------------------
// gemm v3 body: Y[M x 256] = X[M x 256] @ W[256 x 256] + bias.
// 128x128 block tile, 8x8 micro-tile (64 FMA per 4 ds_read_b128), BK=16,
// double-buffered LDS (33.8 KB), register prefetch, 1 barrier per chunk.
// ---------------------------------------------------------------------------
__device__ __forceinline__ void gemm_body(
    const float* __restrict__ X, const float* __restrict__ W,
    const float* __restrict__ bias, float* __restrict__ Y)
{
  __shared__ float As[2][16][132];   // [k][m], stride 132 (33 quads, odd -> conflict-free)
  __shared__ float Bs[2][16][132];   // [k][n]
  const int t = threadIdx.x;
  const int m0 = blockIdx.x * 128;
  const int n0 = blockIdx.y * 128;
  const int tm = t >> 4, tn = t & 15;       // micro-tile: rows 8*tm.., cols 8*tn..
  const int rA = t >> 1;                    // A staging: row 0..127
  const int hA = (t & 1) * 8;               // k-offset 0 or 8 within 16-float chunk
  const int kB = t >> 4;                    // B staging: k row 0..15
  const int qB = t & 15;                    // B col quad (cols 4qB and 64+4qB)

  float acc[8][8];
#pragma unroll
  for (int i = 0; i < 8; ++i)
#pragma unroll
    for (int j = 0; j < 8; ++j) acc[i][j] = 0.f;

  const float* xrow = X + (size_t)(m0 + rA) * 256;

  // prologue: stage chunk 0 into buffer 0
  {
    float4 a0 = *(const float4*)&xrow[hA];
    float4 a1 = *(const float4*)&xrow[hA + 4];
    float4 b0 = *(const float4*)&W[(size_t)kB * 256 + n0 + 4 * qB];
    float4 b1 = *(const float4*)&W[(size_t)kB * 256 + n0 + 64 + 4 * qB];
    As[0][hA + 0][rA] = a0.x; As[0][hA + 1][rA] = a0.y;
    As[0][hA + 2][rA] = a0.z; As[0][hA + 3][rA] = a0.w;
    As[0][hA + 4][rA] = a1.x; As[0][hA + 5][rA] = a1.y;
    As[0][hA + 6][rA] = a1.z; As[0][hA + 7][rA] = a1.w;
    *(float4*)&Bs[0][kB][4 * qB] = b0;
    *(float4*)&Bs[0][kB][64 + 4 * qB] = b1;
  }
  __syncthreads();

  int cur = 0;
  for (int k0 = 0; k0 < 256; k0 += 16) {
    const bool more = (k0 + 16) < 256;
    float4 na0 = {0,0,0,0}, na1 = {0,0,0,0}, nb0 = {0,0,0,0}, nb1 = {0,0,0,0};
    if (more) {                      // prefetch next chunk into registers
      na0 = *(const float4*)&xrow[k0 + 16 + hA];
      na1 = *(const float4*)&xrow[k0 + 16 + hA + 4];
      nb0 = *(const float4*)&W[(size_t)(k0 + 16 + kB) * 256 + n0 + 4 * qB];
      nb1 = *(const float4*)&W[(size_t)(k0 + 16 + kB) * 256 + n0 + 64 + 4 * qB];
    }
#pragma unroll
    for (int kk = 0; kk < 16; ++kk) {
      float4 av0 = *(const float4*)&As[cur][kk][8 * tm];
      float4 av1 = *(const float4*)&As[cur][kk][8 * tm + 4];
      float4 bv0 = *(const float4*)&Bs[cur][kk][8 * tn];
      float4 bv1 = *(const float4*)&Bs[cur][kk][8 * tn + 4];
      float ar[8] = {av0.x, av0.y, av0.z, av0.w, av1.x, av1.y, av1.z, av1.w};
      float br[8] = {bv0.x, bv0.y, bv0.z, bv0.w, bv1.x, bv1.y, bv1.z, bv1.w};
#pragma unroll
      for (int i = 0; i < 8; ++i)
#pragma unroll
        for (int j = 0; j < 8; ++j) acc[i][j] = fmaf(ar[i], br[j], acc[i][j]);
    }
    if (more) {
      const int nxt = cur ^ 1;
      As[nxt][hA + 0][rA] = na0.x; As[nxt][hA + 1][rA] = na0.y;
      As[nxt][hA + 2][rA] = na0.z; As[nxt][hA + 3][rA] = na0.w;
      As[nxt][hA + 4][rA] = na1.x; As[nxt][hA + 5][rA] = na1.y;
      As[nxt][hA + 6][rA] = na1.z; As[nxt][hA + 7][rA] = na1.w;
      *(float4*)&Bs[nxt][kB][4 * qB] = nb0;
      *(float4*)&Bs[nxt][kB][64 + 4 * qB] = nb1;
      __syncthreads();
      cur = nxt;
    }
  }

  float4 bb0 = *(const float4*)&bias[n0 + 8 * tn];
  float4 bb1 = *(const float4*)&bias[n0 + 8 * tn + 4];
#pragma unroll
  for (int i = 0; i < 8; ++i) {
    float4 o0, o1;
    o0.x = acc[i][0] + bb0.x; o0.y = acc[i][1] + bb0.y;
    o0.z = acc[i][2] + bb0.z; o0.w = acc[i][3] + bb0.w;
    o1.x = acc[i][4] + bb1.x; o1.y = acc[i][5] + bb1.y;
    o1.z = acc[i][6] + bb1.z; o1.w = acc[i][7] + bb1.w;
    float* yr = &Y[(size_t)(m0 + 8 * tm + i) * 256 + n0 + 8 * tn];
    *(float4*)&yr[0] = o0;
    *(float4*)&yr[4] = o1;
  }
}

// fused Q/K/V projection: z picks input / weight slice / output slice
__global__ __launch_bounds__(256, 3) void gemm_qkv_kernel(
    const float* __restrict__ q, const float* __restrict__ k,
    const float* __restrict__ v, const float* __restrict__ Wcat,
    const float* __restrict__ bcat, float* __restrict__ Yb)
{
  const int z = blockIdx.z;
  const float* X = (z == 0) ? q : (z == 1) ? k : v;
  gemm_body(X, Wcat + z * 65536, bcat + (z << 8), Yb + (size_t)z * 4194304);
}

__global__ __launch_bounds__(256, 3) void gemm_out_kernel(
    const float* __restrict__ X, const float* __restrict__ W,
    const float* __restrict__ bias, float* __restrict__ Y)
{
  gemm_body(X, W, bias, Y);
}

// ---------------------------------------------------------------------------
// dist_stats: per (b,q) row of dist+neg -> 1/sum(exp). No max subtraction:
// dist in [0,1), masked entries exp(-1e9) -> 0; f32-safe.
// ---------------------------------------------------------------------------
__global__ __launch_bounds__(256) void dist_stats_kernel(
    const float* __restrict__ dist, const float* __restrict__ mask,
    float* __restrict__ dinv)
{
  const int t = threadIdx.x;
  const int w = t >> 6, lane = t & 63;
  const int row = blockIdx.x * 4 + w;
  const int b = row >> 10;
  const float* dr = dist + (size_t)row * 1024;
  const float* mr = mask + b * 1024;
  float s = 0.f;
#pragma unroll
  for (int j = 0; j < 16; ++j) {
    int c = lane + 64 * j;
    s += __expf(dr[c] - 1e9f * mr[c]);
  }
#pragma unroll
  for (int off = 32; off >= 1; off >>= 1) s += __shfl_xor(s, off);
  if (lane == 0) dinv[row] = 1.0f / s;
}

// ---------------------------------------------------------------------------
// attn_fused v3: block = (b, h, 16 q-rows); 4 waves, each wave owns 4 q-rows,
// each lane owns ONE column per 64-column K/V tile.
//   - no-max softmax: phase 1 stores e=exp(logit) directly into Ls and
//     accumulates row-sums in registers -> entire stats phase removed
//   - epilogue: wave-local XOR-swizzled transpose-reduce in the wave's own
//     Ls row region -> zero epilogue barriers
//   - wout stores nontemporal (write-once 512 MB; keep L2 for dist/adj/K/V)
// LDS = 16x1024 (Ls) + 64x36 (KVs) = 74,752 B -> 2 blocks/CU.
// ---------------------------------------------------------------------------
__global__ __launch_bounds__(256, 2) void attn_fused_kernel(
    const float* __restrict__ Qc, const float* __restrict__ Kc,
    const float* __restrict__ Vc, const float* __restrict__ mask,
    const float* __restrict__ adj, const float* __restrict__ dist,
    const float* __restrict__ dinv,
    float* __restrict__ wout, float* __restrict__ conc)
{
  __shared__ float Ls[16384];      // [16][1024] e-values; epilogue: per-wave [64][64] swizzled
  __shared__ float KVs[64][36];    // K-tile, then V-tile staging (stride 36 = 9 quads, odd)
  const int t = threadIdx.x;
  const int bid = blockIdx.x;
  const int qb = bid & 63, h = (bid >> 6) & 7, b = bid >> 9;
  const int q0 = qb * 16;
  const int branch = h >> 2;
  const int boff = branch * 128 + (h & 3) * 32;
  const int wv = t >> 6, l = t & 63;     // wave id, lane id
  const int gr = q0 + 4 * wv;            // wave's first global q-row
  const int sr = t >> 2, sq = t & 3;     // staging: row sr (0..63), dim-quads sq, sq+4

  // ---- Q rows for this wave into registers (dead after phase 1) ----
  float Q[4][32];
  const float* qbase = Qc + ((size_t)(b * 1024 + gr)) * 256 + boff;
#pragma unroll
  for (int r = 0; r < 4; ++r)
#pragma unroll
    for (int dq = 0; dq < 8; ++dq) {
      float4 a = *(const float4*)&qbase[(size_t)r * 256 + 4 * dq];
      Q[r][4 * dq + 0] = a.x; Q[r][4 * dq + 1] = a.y;
      Q[r][4 * dq + 2] = a.z; Q[r][4 * dq + 3] = a.w;
    }

  const float* kb = Kc + (size_t)(b * 1024) * 256 + boff;
  const float* mr = mask + b * 1024;

  // -------- Phase 1: e-values -> Ls, row-sums in registers --------
  float sp0 = 0.f, sp1 = 0.f, sp2 = 0.f, sp3 = 0.f;
  {
    float4 ka  = *(const float4*)&kb[(size_t)sr * 256 + 4 * sq];
    float4 kc2 = *(const float4*)&kb[(size_t)sr * 256 + 16 + 4 * sq];
    *(float4*)&KVs[sr][4 * sq] = ka;
    *(float4*)&KVs[sr][16 + 4 * sq] = kc2;
    __syncthreads();
  }
  float ngc = -1e9f * mr[l];
  for (int cc = 0; cc < 16; ++cc) {
    float4 nka, nkc2; float nng = 0.f;
    if (cc < 15) {
      const int cn0 = (cc + 1) * 64;
      nka  = *(const float4*)&kb[(size_t)(cn0 + sr) * 256 + 4 * sq];
      nkc2 = *(const float4*)&kb[(size_t)(cn0 + sr) * 256 + 16 + 4 * sq];
      nng = -1e9f * mr[cn0 + l];
    }
    const int c = cc * 64 + l;
    float s0 = 0.f, s1 = 0.f, s2 = 0.f, s3 = 0.f;
#pragma unroll
    for (int dq = 0; dq < 8; ++dq) {
      float4 kv = *(const float4*)&KVs[l][4 * dq];   // stride 36: conflict-free
      s0 = fmaf(Q[0][4 * dq + 0], kv.x, s0); s0 = fmaf(Q[0][4 * dq + 1], kv.y, s0);
      s0 = fmaf(Q[0][4 * dq + 2], kv.z, s0); s0 = fmaf(Q[0][4 * dq + 3], kv.w, s0);
      s1 = fmaf(Q[1][4 * dq + 0], kv.x, s1); s1 = fmaf(Q[1][4 * dq + 1], kv.y, s1);
      s1 = fmaf(Q[1][4 * dq + 2], kv.z, s1); s1 = fmaf(Q[1][4 * dq + 3], kv.w, s1);
      s2 = fmaf(Q[2][4 * dq + 0], kv.x, s2); s2 = fmaf(Q[2][4 * dq + 1], kv.y, s2);
      s2 = fmaf(Q[2][4 * dq + 2], kv.z, s2); s2 = fmaf(Q[2][4 * dq + 3], kv.w, s2);
      s3 = fmaf(Q[3][4 * dq + 0], kv.x, s3); s3 = fmaf(Q[3][4 * dq + 1], kv.y, s3);
      s3 = fmaf(Q[3][4 * dq + 2], kv.z, s3); s3 = fmaf(Q[3][4 * dq + 3], kv.w, s3);
    }
    float e0 = __expf(fmaf(s0, SCALE, ngc));
    float e1 = __expf(fmaf(s1, SCALE, ngc));
    float e2 = __expf(fmaf(s2, SCALE, ngc));
    float e3 = __expf(fmaf(s3, SCALE, ngc));
    Ls[(4 * wv + 0) * 1024 + c] = e0;
    Ls[(4 * wv + 1) * 1024 + c] = e1;
    Ls[(4 * wv + 2) * 1024 + c] = e2;
    Ls[(4 * wv + 3) * 1024 + c] = e3;
    sp0 += e0; sp1 += e1; sp2 += e2; sp3 += e3;
    if (cc < 15) {
      __syncthreads();
      *(float4*)&KVs[sr][4 * sq] = nka;
      *(float4*)&KVs[sr][16 + 4 * sq] = nkc2;
      __syncthreads();
      ngc = nng;
    }
  }

  // -------- row-sum reduce (registers + shuffle only) --------
#pragma unroll
  for (int off = 32; off >= 1; off >>= 1) {
    sp0 += __shfl_xor(sp0, off);
    sp1 += __shfl_xor(sp1, off);
    sp2 += __shfl_xor(sp2, off);
    sp3 += __shfl_xor(sp3, off);
  }
  float inv[4] = {1.0f / sp0, 1.0f / sp1, 1.0f / sp2, 1.0f / sp3};

  // -------- Phase 2: reweight + w write + PV accumulate --------
  float o[4][32];
#pragma unroll
  for (int r = 0; r < 4; ++r)
#pragma unroll
    for (int d = 0; d < 32; ++d) o[r][d] = 0.f;

  const float* br_[4];
  float din[4];
  if (branch == 0) {
#pragma unroll
    for (int r = 0; r < 4; ++r) {
      din[r] = dinv[b * 1024 + gr + r];
      br_[r] = dist + (size_t)(b * 1024 + gr + r) * 1024;
    }
  } else {
#pragma unroll
    for (int r = 0; r < 4; ++r) {
      din[r] = 0.f;
      br_[r] = adj + (size_t)(b * 1024 + gr + r) * 1024;
    }
  }
  const float* vb = Vc + (size_t)(b * 1024) * 256 + boff;
  const size_t wr0 = ((size_t)(b * 8 + h) * 1024 + gr) * 1024;

  float fpre[4], ngc2;
  {
    float4 va  = *(const float4*)&vb[(size_t)sr * 256 + 4 * sq];
    float4 vc2 = *(const float4*)&vb[(size_t)sr * 256 + 16 + 4 * sq];
#pragma unroll
    for (int r = 0; r < 4; ++r) fpre[r] = br_[r][l];
    ngc2 = -1e9f * mr[l];
    __syncthreads();                     // all waves done reading last K tile
    *(float4*)&KVs[sr][4 * sq] = va;
    *(float4*)&KVs[sr][16 + 4 * sq] = vc2;
    __syncthreads();
  }
  for (int cc = 0; cc < 16; ++cc) {
    const int c = cc * 64 + l;
    float4 nva, nvc2; float nf[4]; float nng = 0.f;
    if (cc < 15) {
      const int cn0 = (cc + 1) * 64;
      nva  = *(const float4*)&vb[(size_t)(cn0 + sr) * 256 + 4 * sq];
      nvc2 = *(const float4*)&vb[(size_t)(cn0 + sr) * 256 + 16 + 4 * sq];
#pragma unroll
      for (int r = 0; r < 4; ++r) nf[r] = br_[r][cn0 + l];
      nng = -1e9f * mr[cn0 + l];
    }
    float w[4];
#pragma unroll
    for (int r = 0; r < 4; ++r) {
      float e = Ls[(4 * wv + r) * 1024 + c] * inv[r];
      float f;
      if (branch == 0) f = __expf(fpre[r] + ngc2) * din[r];
      else             f = fpre[r];
      w[r] = e * f;
      __builtin_nontemporal_store(w[r], &wout[wr0 + (size_t)r * 1024 + c]);
    }
#pragma unroll
    for (int dq = 0; dq < 8; ++dq) {
      float4 vv = *(const float4*)&KVs[l][4 * dq];
      o[0][4 * dq + 0] = fmaf(w[0], vv.x, o[0][4 * dq + 0]);
      o[0][4 * dq + 1] = fmaf(w[0], vv.y, o[0][4 * dq + 1]);
      o[0][4 * dq + 2] = fmaf(w[0], vv.z, o[0][4 * dq + 2]);
      o[0][4 * dq + 3] = fmaf(w[0], vv.w, o[0][4 * dq + 3]);
      o[1][4 * dq + 0] = fmaf(w[1], vv.x, o[1][4 * dq + 0]);
      o[1][4 * dq + 1] = fmaf(w[1], vv.y, o[1][4 * dq + 1]);
      o[1][4 * dq + 2] = fmaf(w[1], vv.z, o[1][4 * dq + 2]);
      o[1][4 * dq + 3] = fmaf(w[1], vv.w, o[1][4 * dq + 3]);
      o[2][4 * dq + 0] = fmaf(w[2], vv.x, o[2][4 * dq + 0]);
      o[2][4 * dq + 1] = fmaf(w[2], vv.y, o[2][4 * dq + 1]);
      o[2][4 * dq + 2] = fmaf(w[2], vv.z, o[2][4 * dq + 2]);
      o[2][4 * dq + 3] = fmaf(w[2], vv.w, o[2][4 * dq + 3]);
      o[3][4 * dq + 0] = fmaf(w[3], vv.x, o[3][4 * dq + 0]);
      o[3][4 * dq + 1] = fmaf(w[3], vv.y, o[3][4 * dq + 1]);
      o[3][4 * dq + 2] = fmaf(w[3], vv.z, o[3][4 * dq + 2]);
      o[3][4 * dq + 3] = fmaf(w[3], vv.w, o[3][4 * dq + 3]);
    }
    if (cc < 15) {
      __syncthreads();
      *(float4*)&KVs[sr][4 * sq] = nva;
      *(float4*)&KVs[sr][16 + 4 * sq] = nvc2;
      __syncthreads();
#pragma unroll
      for (int r = 0; r < 4; ++r) fpre[r] = nf[r];
      ngc2 = nng;
    }
  }

  // -------- Epilogue: wave-local swizzled transpose-reduce (no barriers) ----
  // Scratch = this wave's own Ls row region (4096 floats), safe: only this
  // wave ever reads/writes rows 4wv..4wv+3, and its phase-2 reads are done.
  {
    float* Ws_ = &Ls[wv * 4096];
#pragma unroll
    for (int p = 0; p < 2; ++p) {
      // write rows 2p, 2p+1 (64 floats/lane) as 32 swizzled float2
#pragma unroll
      for (int j = 0; j < 32; ++j) {
        const int r = j >> 4, d2 = j & 15;             // row 2p+r, dims 2d2..2d2+1
        const int slot = (j + l) & 31;
        float2 u;
        u.x = o[2 * p + r][2 * d2];
        u.y = o[2 * p + r][2 * d2 + 1];
        *(float2*)&Ws_[l * 64 + 2 * slot] = u;
      }
      // wave-synchronous transpose-read: lane reduces (row 2p+rp, dim d)
      const int rp = l >> 5, d = l & 31;
      const int jc = rp * 16 + (d >> 1);
      float a = 0.f;
#pragma unroll
      for (int ll = 0; ll < 64; ++ll)
        a += Ws_[ll * 64 + 2 * ((jc + ll) & 31) + (d & 1)];
      conc[((size_t)(b * 1024) + q0 + 4 * wv + 2 * p + rp) * 256 + boff + d] = a;
    }
  }
}

// ---------------------------------------------------------------------------
extern "C" void kernel_launch(void* const* d_in, const int* in_sizes, int n_in,
                              void* d_out, int out_size, void* d_ws, size_t ws_size,
                              hipStream_t stream)
{
  const float* v_ori = (const float*)d_in[0];
  const float* k_ori = (const float*)d_in[1];
  const float* q_ori = (const float*)d_in[2];
  const float* mask  = (const float*)d_in[3];
  const float* adj   = (const float*)d_in[4];
  const float* dist  = (const float*)d_in[5];
  const float* Wqd = (const float*)d_in[6];  const float* bqd = (const float*)d_in[7];
  const float* Wkd = (const float*)d_in[8];  const float* bkd = (const float*)d_in[9];
  const float* Wvd = (const float*)d_in[10]; const float* bvd = (const float*)d_in[11];
  const float* Wqa = (const float*)d_in[12]; const float* bqa = (const float*)d_in[13];
  const float* Wka = (const float*)d_in[14]; const float* bka = (const float*)d_in[15];
  const float* Wva = (const float*)d_in[16]; const float* bva = (const float*)d_in[17];
  const float* Wo  = (const float*)d_in[18]; const float* bo  = (const float*)d_in[19];

  float* out = (float*)d_out;
  float* ws  = (float*)d_ws;
  float* Qc    = ws;                  // 16384*256 (Qc,Kc,Vc contiguous for fused gemm)
  float* Kc    = Qc + 4194304;
  float* Vc    = Kc + 4194304;
  float* conc  = Vc + 4194304;        // 16384*256
  float* dinvb = conc + 4194304;      // 16384
  float* Wcat  = dinvb + 16384;       // 3*65536
  float* bcat  = Wcat + 196608;       // 3*256

  pack_kernel<<<771, 256, 0, stream>>>(Wqd, Wqa, Wkd, Wka, Wvd, Wva,
                                       bqd, bqa, bkd, bka, bvd, bva, Wcat, bcat);
  gemm_qkv_kernel<<<dim3(128, 2, 3), 256, 0, stream>>>(q_ori, k_ori, v_ori,
                                                       Wcat, bcat, Qc);
  dist_stats_kernel<<<4096, 256, 0, stream>>>(dist, mask, dinvb);
  attn_fused_kernel<<<8192, 256, 0, stream>>>(Qc, Kc, Vc, mask, adj, dist,
                                              dinvb, out + OUTW, conc);
  gemm_out_kernel<<<dim3(128, 2), 256, 0, stream>>>(conc, Wo, bo, out);
}

// Round 3
// 1190.107 us; speedup vs baseline: 1.1510x; 1.1510x over previous
//
#include <hip/hip_runtime.h>
#include <cstddef>

// Problem constants (B=16, S=1024, D=256, H=8 -> H2=4 heads/branch, DEPTH=32, DH=128)
static constexpr int BB = 16, SS = 1024, DD = 256;
static constexpr size_t OUTW = (size_t)BB * SS * DD;          // 4,194,304 floats: start of attn_w in d_out
#define SCALE 0.17677669529663687f                             // 1/sqrt(32)

// ---------------------------------------------------------------------------
// pack: Wcat[g] = [W_dist | W_adj] (256x256) for g in {q,k,v}; bcat likewise
// ---------------------------------------------------------------------------
__global__ __launch_bounds__(256) void pack_kernel(
    const float* __restrict__ Wqd, const float* __restrict__ Wqa,
    const float* __restrict__ Wkd, const float* __restrict__ Wka,
    const float* __restrict__ Wvd, const float* __restrict__ Wva,
    const float* __restrict__ bqd, const float* __restrict__ bqa,
    const float* __restrict__ bkd, const float* __restrict__ bka,
    const float* __restrict__ bvd, const float* __restrict__ bva,
    float* __restrict__ Wcat, float* __restrict__ bcat)
{
  int i = blockIdx.x * 256 + threadIdx.x;
  if (i < 3 * 256 * 256) {
    int g = i >> 16, r = (i >> 8) & 255, n = i & 255;
    const float* W0 = (g == 0) ? Wqd : (g == 1) ? Wkd : Wvd;
    const float* W1 = (g == 0) ? Wqa : (g == 1) ? Wka : Wva;
    Wcat[i] = (n < 128) ? W0[r * 128 + n] : W1[r * 128 + (n - 128)];
  } else {
    int j = i - 3 * 256 * 256;
    if (j < 3 * 256) {
      int g = j >> 8, n = j & 255;
      const float* b0 = (g == 0) ? bqd : (g == 1) ? bkd : bvd;
      const float* b1 = (g == 0) ? bqa : (g == 1) ? bka : bva;
      bcat[j] = (n < 128) ? b0[n] : b1[n - 128];
    }
  }
}

// ---------------------------------------------------------------------------
// gemm v4 (W-resident): Y[M x 256] = X[M x 256] @ W[256 x 256] + bias.
// Block = 128 rows x 32 cols. W-slice [256][32] (32 KB) staged in LDS ONCE
// (single barrier), then a barrier-free main loop: each thread streams 4 rows
// from global (register prefetch, 8-way lane dedup -> L1 broadcast) against
// W fragments from LDS (8 quads x 8-lane broadcast, conflict-free).
// Grid (M/128, 8) = 1024 blocks = 4 blocks/CU = 4 waves/SIMD.
// Per thread: 4x4 outputs, 4096 FMA, 256 LDS b128, 256 global float4.
// ---------------------------------------------------------------------------
__device__ __forceinline__ void gemm_body(
    const float* __restrict__ X, const float* __restrict__ W,
    const float* __restrict__ bias, float* __restrict__ Y)
{
  __shared__ float Wl[256 * 32];     // [k][c_local], stride 32 words
  const int t = threadIdx.x;
  const int m0 = blockIdx.x * 128;
  const int n0 = blockIdx.y * 32;
  const int tr = t >> 3;             // row group 0..31 -> rows m0 + 4*tr ..
  const int tc4 = (t & 7) * 4;       // col offset 0,4,..,28 within slice

  // ---- stage W slice (one-time, one barrier) ----
#pragma unroll
  for (int i = 0; i < 8; ++i) {
    const int k = (t >> 3) + 32 * i;
    *(float4*)&Wl[k * 32 + tc4] = *(const float4*)&W[(size_t)k * 256 + n0 + tc4];
  }
  __syncthreads();

  float acc[4][4];
#pragma unroll
  for (int i = 0; i < 4; ++i)
#pragma unroll
    for (int j = 0; j < 4; ++j) acc[i][j] = 0.f;

  const float* xr = X + (size_t)(m0 + 4 * tr) * 256;

  // prologue: load k-chunk 0
  float4 a[4], an[4];
#pragma unroll
  for (int r = 0; r < 4; ++r) a[r] = *(const float4*)&xr[r * 256];

#pragma unroll 2
  for (int k = 0; k < 252; k += 4) {
    // prefetch next chunk (latency hides under 64 FMA + 4 waves/SIMD TLP)
#pragma unroll
    for (int r = 0; r < 4; ++r) an[r] = *(const float4*)&xr[r * 256 + k + 4];
    float4 w0 = *(const float4*)&Wl[(k + 0) * 32 + tc4];
    float4 w1 = *(const float4*)&Wl[(k + 1) * 32 + tc4];
    float4 w2 = *(const float4*)&Wl[(k + 2) * 32 + tc4];
    float4 w3 = *(const float4*)&Wl[(k + 3) * 32 + tc4];
#pragma unroll
    for (int r = 0; r < 4; ++r) {
      acc[r][0] = fmaf(a[r].x, w0.x, acc[r][0]);
      acc[r][1] = fmaf(a[r].x, w0.y, acc[r][1]);
      acc[r][2] = fmaf(a[r].x, w0.z, acc[r][2]);
      acc[r][3] = fmaf(a[r].x, w0.w, acc[r][3]);
      acc[r][0] = fmaf(a[r].y, w1.x, acc[r][0]);
      acc[r][1] = fmaf(a[r].y, w1.y, acc[r][1]);
      acc[r][2] = fmaf(a[r].y, w1.z, acc[r][2]);
      acc[r][3] = fmaf(a[r].y, w1.w, acc[r][3]);
      acc[r][0] = fmaf(a[r].z, w2.x, acc[r][0]);
      acc[r][1] = fmaf(a[r].z, w2.y, acc[r][1]);
      acc[r][2] = fmaf(a[r].z, w2.z, acc[r][2]);
      acc[r][3] = fmaf(a[r].z, w2.w, acc[r][3]);
      acc[r][0] = fmaf(a[r].w, w3.x, acc[r][0]);
      acc[r][1] = fmaf(a[r].w, w3.y, acc[r][1]);
      acc[r][2] = fmaf(a[r].w, w3.z, acc[r][2]);
      acc[r][3] = fmaf(a[r].w, w3.w, acc[r][3]);
    }
#pragma unroll
    for (int r = 0; r < 4; ++r) a[r] = an[r];
  }
  {   // epilogue chunk k = 252
    const int k = 252;
    float4 w0 = *(const float4*)&Wl[(k + 0) * 32 + tc4];
    float4 w1 = *(const float4*)&Wl[(k + 1) * 32 + tc4];
    float4 w2 = *(const float4*)&Wl[(k + 2) * 32 + tc4];
    float4 w3 = *(const float4*)&Wl[(k + 3) * 32 + tc4];
#pragma unroll
    for (int r = 0; r < 4; ++r) {
      acc[r][0] = fmaf(a[r].x, w0.x, acc[r][0]);
      acc[r][1] = fmaf(a[r].x, w0.y, acc[r][1]);
      acc[r][2] = fmaf(a[r].x, w0.z, acc[r][2]);
      acc[r][3] = fmaf(a[r].x, w0.w, acc[r][3]);
      acc[r][0] = fmaf(a[r].y, w1.x, acc[r][0]);
      acc[r][1] = fmaf(a[r].y, w1.y, acc[r][1]);
      acc[r][2] = fmaf(a[r].y, w1.z, acc[r][2]);
      acc[r][3] = fmaf(a[r].y, w1.w, acc[r][3]);
      acc[r][0] = fmaf(a[r].z, w2.x, acc[r][0]);
      acc[r][1] = fmaf(a[r].z, w2.y, acc[r][1]);
      acc[r][2] = fmaf(a[r].z, w2.z, acc[r][2]);
      acc[r][3] = fmaf(a[r].z, w2.w, acc[r][3]);
      acc[r][0] = fmaf(a[r].w, w3.x, acc[r][0]);
      acc[r][1] = fmaf(a[r].w, w3.y, acc[r][1]);
      acc[r][2] = fmaf(a[r].w, w3.z, acc[r][2]);
      acc[r][3] = fmaf(a[r].w, w3.w, acc[r][3]);
    }
  }

  const float4 bb = *(const float4*)&bias[n0 + tc4];
#pragma unroll
  for (int r = 0; r < 4; ++r) {
    float4 o;
    o.x = acc[r][0] + bb.x; o.y = acc[r][1] + bb.y;
    o.z = acc[r][2] + bb.z; o.w = acc[r][3] + bb.w;
    *(float4*)&Y[(size_t)(m0 + 4 * tr + r) * 256 + n0 + tc4] = o;
  }
}

// fused Q/K/V projection: z picks input / weight slice / output slice
__global__ __launch_bounds__(256, 4) void gemm_qkv_kernel(
    const float* __restrict__ q, const float* __restrict__ k,
    const float* __restrict__ v, const float* __restrict__ Wcat,
    const float* __restrict__ bcat, float* __restrict__ Yb)
{
  const int z = blockIdx.z;
  const float* X = (z == 0) ? q : (z == 1) ? k : v;
  gemm_body(X, Wcat + z * 65536, bcat + (z << 8), Yb + (size_t)z * 4194304);
}

__global__ __launch_bounds__(256, 4) void gemm_out_kernel(
    const float* __restrict__ X, const float* __restrict__ W,
    const float* __restrict__ bias, float* __restrict__ Y)
{
  gemm_body(X, W, bias, Y);
}

// ---------------------------------------------------------------------------
// dist_stats: per (b,q) row of dist+neg -> 1/sum(exp). No max subtraction:
// dist in [0,1), masked entries exp(-1e9) -> 0; f32-safe.
// ---------------------------------------------------------------------------
__global__ __launch_bounds__(256) void dist_stats_kernel(
    const float* __restrict__ dist, const float* __restrict__ mask,
    float* __restrict__ dinv)
{
  const int t = threadIdx.x;
  const int w = t >> 6, lane = t & 63;
  const int row = blockIdx.x * 4 + w;
  const int b = row >> 10;
  const float* dr = dist + (size_t)row * 1024;
  const float* mr = mask + b * 1024;
  float s = 0.f;
#pragma unroll
  for (int j = 0; j < 16; ++j) {
    int c = lane + 64 * j;
    s += __expf(dr[c] - 1e9f * mr[c]);
  }
#pragma unroll
  for (int off = 32; off >= 1; off >>= 1) s += __shfl_xor(s, off);
  if (lane == 0) dinv[row] = 1.0f / s;
}

// ---------------------------------------------------------------------------
// attn_fused v3 (unchanged from round 2): block = (b, h, 16 q-rows); 4 waves,
// each wave owns 4 q-rows, each lane owns ONE column per 64-column K/V tile.
//   - no-max softmax: phase 1 stores e=exp(logit) directly into Ls and
//     accumulates row-sums in registers
//   - epilogue: wave-local XOR-swizzled transpose-reduce, zero barriers
//   - wout stores nontemporal
// LDS = 16x1024 (Ls) + 64x36 (KVs) = 74,752 B -> 2 blocks/CU.
// ---------------------------------------------------------------------------
__global__ __launch_bounds__(256, 2) void attn_fused_kernel(
    const float* __restrict__ Qc, const float* __restrict__ Kc,
    const float* __restrict__ Vc, const float* __restrict__ mask,
    const float* __restrict__ adj, const float* __restrict__ dist,
    const float* __restrict__ dinv,
    float* __restrict__ wout, float* __restrict__ conc)
{
  __shared__ float Ls[16384];      // [16][1024] e-values; epilogue: per-wave [64][64] swizzled
  __shared__ float KVs[64][36];    // K-tile, then V-tile staging (stride 36 = 9 quads, odd)
  const int t = threadIdx.x;
  const int bid = blockIdx.x;
  const int qb = bid & 63, h = (bid >> 6) & 7, b = bid >> 9;
  const int q0 = qb * 16;
  const int branch = h >> 2;
  const int boff = branch * 128 + (h & 3) * 32;
  const int wv = t >> 6, l = t & 63;     // wave id, lane id
  const int gr = q0 + 4 * wv;            // wave's first global q-row
  const int sr = t >> 2, sq = t & 3;     // staging: row sr (0..63), dim-quads sq, sq+4

  // ---- Q rows for this wave into registers (dead after phase 1) ----
  float Q[4][32];
  const float* qbase = Qc + ((size_t)(b * 1024 + gr)) * 256 + boff;
#pragma unroll
  for (int r = 0; r < 4; ++r)
#pragma unroll
    for (int dq = 0; dq < 8; ++dq) {
      float4 a = *(const float4*)&qbase[(size_t)r * 256 + 4 * dq];
      Q[r][4 * dq + 0] = a.x; Q[r][4 * dq + 1] = a.y;
      Q[r][4 * dq + 2] = a.z; Q[r][4 * dq + 3] = a.w;
    }

  const float* kb = Kc + (size_t)(b * 1024) * 256 + boff;
  const float* mr = mask + b * 1024;

  // -------- Phase 1: e-values -> Ls, row-sums in registers --------
  float sp0 = 0.f, sp1 = 0.f, sp2 = 0.f, sp3 = 0.f;
  {
    float4 ka  = *(const float4*)&kb[(size_t)sr * 256 + 4 * sq];
    float4 kc2 = *(const float4*)&kb[(size_t)sr * 256 + 16 + 4 * sq];
    *(float4*)&KVs[sr][4 * sq] = ka;
    *(float4*)&KVs[sr][16 + 4 * sq] = kc2;
    __syncthreads();
  }
  float ngc = -1e9f * mr[l];
  for (int cc = 0; cc < 16; ++cc) {
    float4 nka, nkc2; float nng = 0.f;
    if (cc < 15) {
      const int cn0 = (cc + 1) * 64;
      nka  = *(const float4*)&kb[(size_t)(cn0 + sr) * 256 + 4 * sq];
      nkc2 = *(const float4*)&kb[(size_t)(cn0 + sr) * 256 + 16 + 4 * sq];
      nng = -1e9f * mr[cn0 + l];
    }
    const int c = cc * 64 + l;
    float s0 = 0.f, s1 = 0.f, s2 = 0.f, s3 = 0.f;
#pragma unroll
    for (int dq = 0; dq < 8; ++dq) {
      float4 kv = *(const float4*)&KVs[l][4 * dq];
      s0 = fmaf(Q[0][4 * dq + 0], kv.x, s0); s0 = fmaf(Q[0][4 * dq + 1], kv.y, s0);
      s0 = fmaf(Q[0][4 * dq + 2], kv.z, s0); s0 = fmaf(Q[0][4 * dq + 3], kv.w, s0);
      s1 = fmaf(Q[1][4 * dq + 0], kv.x, s1); s1 = fmaf(Q[1][4 * dq + 1], kv.y, s1);
      s1 = fmaf(Q[1][4 * dq + 2], kv.z, s1); s1 = fmaf(Q[1][4 * dq + 3], kv.w, s1);
      s2 = fmaf(Q[2][4 * dq + 0], kv.x, s2); s2 = fmaf(Q[2][4 * dq + 1], kv.y, s2);
      s2 = fmaf(Q[2][4 * dq + 2], kv.z, s2); s2 = fmaf(Q[2][4 * dq + 3], kv.w, s2);
      s3 = fmaf(Q[3][4 * dq + 0], kv.x, s3); s3 = fmaf(Q[3][4 * dq + 1], kv.y, s3);
      s3 = fmaf(Q[3][4 * dq + 2], kv.z, s3); s3 = fmaf(Q[3][4 * dq + 3], kv.w, s3);
    }
    float e0 = __expf(fmaf(s0, SCALE, ngc));
    float e1 = __expf(fmaf(s1, SCALE, ngc));
    float e2 = __expf(fmaf(s2, SCALE, ngc));
    float e3 = __expf(fmaf(s3, SCALE, ngc));
    Ls[(4 * wv + 0) * 1024 + c] = e0;
    Ls[(4 * wv + 1) * 1024 + c] = e1;
    Ls[(4 * wv + 2) * 1024 + c] = e2;
    Ls[(4 * wv + 3) * 1024 + c] = e3;
    sp0 += e0; sp1 += e1; sp2 += e2; sp3 += e3;
    if (cc < 15) {
      __syncthreads();
      *(float4*)&KVs[sr][4 * sq] = nka;
      *(float4*)&KVs[sr][16 + 4 * sq] = nkc2;
      __syncthreads();
      ngc = nng;
    }
  }

  // -------- row-sum reduce (registers + shuffle only) --------
#pragma unroll
  for (int off = 32; off >= 1; off >>= 1) {
    sp0 += __shfl_xor(sp0, off);
    sp1 += __shfl_xor(sp1, off);
    sp2 += __shfl_xor(sp2, off);
    sp3 += __shfl_xor(sp3, off);
  }
  float inv[4] = {1.0f / sp0, 1.0f / sp1, 1.0f / sp2, 1.0f / sp3};

  // -------- Phase 2: reweight + w write + PV accumulate --------
  float o[4][32];
#pragma unroll
  for (int r = 0; r < 4; ++r)
#pragma unroll
    for (int d = 0; d < 32; ++d) o[r][d] = 0.f;

  const float* br_[4];
  float din[4];
  if (branch == 0) {
#pragma unroll
    for (int r = 0; r < 4; ++r) {
      din[r] = dinv[b * 1024 + gr + r];
      br_[r] = dist + (size_t)(b * 1024 + gr + r) * 1024;
    }
  } else {
#pragma unroll
    for (int r = 0; r < 4; ++r) {
      din[r] = 0.f;
      br_[r] = adj + (size_t)(b * 1024 + gr + r) * 1024;
    }
  }
  const float* vb = Vc + (size_t)(b * 1024) * 256 + boff;
  const size_t wr0 = ((size_t)(b * 8 + h) * 1024 + gr) * 1024;

  float fpre[4], ngc2;
  {
    float4 va  = *(const float4*)&vb[(size_t)sr * 256 + 4 * sq];
    float4 vc2 = *(const float4*)&vb[(size_t)sr * 256 + 16 + 4 * sq];
#pragma unroll
    for (int r = 0; r < 4; ++r) fpre[r] = br_[r][l];
    ngc2 = -1e9f * mr[l];
    __syncthreads();                     // all waves done reading last K tile
    *(float4*)&KVs[sr][4 * sq] = va;
    *(float4*)&KVs[sr][16 + 4 * sq] = vc2;
    __syncthreads();
  }
  for (int cc = 0; cc < 16; ++cc) {
    const int c = cc * 64 + l;
    float4 nva, nvc2; float nf[4]; float nng = 0.f;
    if (cc < 15) {
      const int cn0 = (cc + 1) * 64;
      nva  = *(const float4*)&vb[(size_t)(cn0 + sr) * 256 + 4 * sq];
      nvc2 = *(const float4*)&vb[(size_t)(cn0 + sr) * 256 + 16 + 4 * sq];
#pragma unroll
      for (int r = 0; r < 4; ++r) nf[r] = br_[r][cn0 + l];
      nng = -1e9f * mr[cn0 + l];
    }
    float w[4];
#pragma unroll
    for (int r = 0; r < 4; ++r) {
      float e = Ls[(4 * wv + r) * 1024 + c] * inv[r];
      float f;
      if (branch == 0) f = __expf(fpre[r] + ngc2) * din[r];
      else             f = fpre[r];
      w[r] = e * f;
      __builtin_nontemporal_store(w[r], &wout[wr0 + (size_t)r * 1024 + c]);
    }
#pragma unroll
    for (int dq = 0; dq < 8; ++dq) {
      float4 vv = *(const float4*)&KVs[l][4 * dq];
      o[0][4 * dq + 0] = fmaf(w[0], vv.x, o[0][4 * dq + 0]);
      o[0][4 * dq + 1] = fmaf(w[0], vv.y, o[0][4 * dq + 1]);
      o[0][4 * dq + 2] = fmaf(w[0], vv.z, o[0][4 * dq + 2]);
      o[0][4 * dq + 3] = fmaf(w[0], vv.w, o[0][4 * dq + 3]);
      o[1][4 * dq + 0] = fmaf(w[1], vv.x, o[1][4 * dq + 0]);
      o[1][4 * dq + 1] = fmaf(w[1], vv.y, o[1][4 * dq + 1]);
      o[1][4 * dq + 2] = fmaf(w[1], vv.z, o[1][4 * dq + 2]);
      o[1][4 * dq + 3] = fmaf(w[1], vv.w, o[1][4 * dq + 3]);
      o[2][4 * dq + 0] = fmaf(w[2], vv.x, o[2][4 * dq + 0]);
      o[2][4 * dq + 1] = fmaf(w[2], vv.y, o[2][4 * dq + 1]);
      o[2][4 * dq + 2] = fmaf(w[2], vv.z, o[2][4 * dq + 2]);
      o[2][4 * dq + 3] = fmaf(w[2], vv.w, o[2][4 * dq + 3]);
      o[3][4 * dq + 0] = fmaf(w[3], vv.x, o[3][4 * dq + 0]);
      o[3][4 * dq + 1] = fmaf(w[3], vv.y, o[3][4 * dq + 1]);
      o[3][4 * dq + 2] = fmaf(w[3], vv.z, o[3][4 * dq + 2]);
      o[3][4 * dq + 3] = fmaf(w[3], vv.w, o[3][4 * dq + 3]);
    }
    if (cc < 15) {
      __syncthreads();
      *(float4*)&KVs[sr][4 * sq] = nva;
      *(float4*)&KVs[sr][16 + 4 * sq] = nvc2;
      __syncthreads();
#pragma unroll
      for (int r = 0; r < 4; ++r) fpre[r] = nf[r];
      ngc2 = nng;
    }
  }

  // -------- Epilogue: wave-local swizzled transpose-reduce (no barriers) ----
  {
    float* Ws_ = &Ls[wv * 4096];
#pragma unroll
    for (int p = 0; p < 2; ++p) {
#pragma unroll
      for (int j = 0; j < 32; ++j) {
        const int r = j >> 4, d2 = j & 15;             // row 2p+r, dims 2d2..2d2+1
        const int slot = (j + l) & 31;
        float2 u;
        u.x = o[2 * p + r][2 * d2];
        u.y = o[2 * p + r][2 * d2 + 1];
        *(float2*)&Ws_[l * 64 + 2 * slot] = u;
      }
      const int rp = l >> 5, d = l & 31;
      const int jc = rp * 16 + (d >> 1);
      float a = 0.f;
#pragma unroll
      for (int ll = 0; ll < 64; ++ll)
        a += Ws_[ll * 64 + 2 * ((jc + ll) & 31) + (d & 1)];
      conc[((size_t)(b * 1024) + q0 + 4 * wv + 2 * p + rp) * 256 + boff + d] = a;
    }
  }
}

// ---------------------------------------------------------------------------
extern "C" void kernel_launch(void* const* d_in, const int* in_sizes, int n_in,
                              void* d_out, int out_size, void* d_ws, size_t ws_size,
                              hipStream_t stream)
{
  const float* v_ori = (const float*)d_in[0];
  const float* k_ori = (const float*)d_in[1];
  const float* q_ori = (const float*)d_in[2];
  const float* mask  = (const float*)d_in[3];
  const float* adj   = (const float*)d_in[4];
  const float* dist  = (const float*)d_in[5];
  const float* Wqd = (const float*)d_in[6];  const float* bqd = (const float*)d_in[7];
  const float* Wkd = (const float*)d_in[8];  const float* bkd = (const float*)d_in[9];
  const float* Wvd = (const float*)d_in[10]; const float* bvd = (const float*)d_in[11];
  const float* Wqa = (const float*)d_in[12]; const float* bqa = (const float*)d_in[13];
  const float* Wka = (const float*)d_in[14]; const float* bka = (const float*)d_in[15];
  const float* Wva = (const float*)d_in[16]; const float* bva = (const float*)d_in[17];
  const float* Wo  = (const float*)d_in[18]; const float* bo  = (const float*)d_in[19];

  float* out = (float*)d_out;
  float* ws  = (float*)d_ws;
  float* Qc    = ws;                  // 16384*256 (Qc,Kc,Vc contiguous for fused gemm)
  float* Kc    = Qc + 4194304;
  float* Vc    = Kc + 4194304;
  float* conc  = Vc + 4194304;        // 16384*256
  float* dinvb = conc + 4194304;      // 16384
  float* Wcat  = dinvb + 16384;       // 3*65536
  float* bcat  = Wcat + 196608;       // 3*256

  pack_kernel<<<771, 256, 0, stream>>>(Wqd, Wqa, Wkd, Wka, Wvd, Wva,
                                       bqd, bqa, bkd, bka, bvd, bva, Wcat, bcat);
  gemm_qkv_kernel<<<dim3(128, 8, 3), 256, 0, stream>>>(q_ori, k_ori, v_ori,
                                                       Wcat, bcat, Qc);
  dist_stats_kernel<<<4096, 256, 0, stream>>>(dist, mask, dinvb);
  attn_fused_kernel<<<8192, 256, 0, stream>>>(Qc, Kc, Vc, mask, adj, dist,
                                              dinvb, out + OUTW, conc);
  gemm_out_kernel<<<dim3(128, 8), 256, 0, stream>>>(conc, Wo, bo, out);
}

// Round 4
// 1172.673 us; speedup vs baseline: 1.1681x; 1.0149x over previous
//
#include <hip/hip_runtime.h>
#include <cstddef>

// Problem constants (B=16, S=1024, D=256, H=8 -> H2=4 heads/branch, DEPTH=32, DH=128)
static constexpr int BB = 16, SS = 1024, DD = 256;
static constexpr size_t OUTW = (size_t)BB * SS * DD;          // 4,194,304 floats: start of attn_w in d_out
#define SCALE 0.17677669529663687f                             // 1/sqrt(32)

// Packed f32 pair: lowers to v_pk_fma_f32 (VOP3P) on gfx950 via llvm.fma.v2f32
typedef float f32x2 __attribute__((ext_vector_type(2)));
__device__ __forceinline__ f32x2 fma2(f32x2 a, f32x2 b, f32x2 c) {
#if defined(__has_builtin)
#if __has_builtin(__builtin_elementwise_fma)
  return __builtin_elementwise_fma(a, b, c);
#else
  return (f32x2){fmaf(a.x, b.x, c.x), fmaf(a.y, b.y, c.y)};
#endif
#else
  return (f32x2){fmaf(a.x, b.x, c.x), fmaf(a.y, b.y, c.y)};
#endif
}

// ---------------------------------------------------------------------------
// gemm v5 body (W-resident, packed f32): Y[Mx256] tile = X @ W-slice + bias.
// Block = 128 rows x 32 cols. W-slice [256][32] staged in LDS once (stages
// DIRECTLY from the un-packed source weights -> pack_kernel eliminated).
// Barrier-free main loop, register prefetch, v_pk_fma_f32 inner (32 pk + 16
// splat per 64-FLOP-pair chunk). Grid (M/128, 8 [, z]) = 4 blocks/CU.
// ---------------------------------------------------------------------------
__device__ __forceinline__ void gemm_body(
    const float* __restrict__ X, const float* __restrict__ Wcol, int wstride,
    const float* __restrict__ bcol, float* __restrict__ Y)
{
  __shared__ float Wl[256 * 32];     // [k][c_local]
  const int t = threadIdx.x;
  const int m0 = blockIdx.x * 128;
  const int n0 = blockIdx.y * 32;
  const int tr = t >> 3;             // row group 0..31 -> rows m0 + 4*tr ..
  const int tc4 = (t & 7) * 4;       // col offset 0,4,..,28 within slice

  // ---- stage W slice (one-time, one barrier) ----
#pragma unroll
  for (int i = 0; i < 8; ++i) {
    const int k = (t >> 3) + 32 * i;
    *(float4*)&Wl[k * 32 + tc4] = *(const float4*)&Wcol[(size_t)k * wstride + tc4];
  }
  __syncthreads();

  f32x2 acc[4][2];                   // 4 rows x (2 col-pairs)
#pragma unroll
  for (int i = 0; i < 4; ++i) {
    acc[i][0] = (f32x2){0.f, 0.f};
    acc[i][1] = (f32x2){0.f, 0.f};
  }

  const float* xr = X + (size_t)(m0 + 4 * tr) * 256;

  float4 a[4], an[4];
#pragma unroll
  for (int r = 0; r < 4; ++r) a[r] = *(const float4*)&xr[r * 256];

#define GEMM_CHUNK(KK)                                                        \
  {                                                                           \
    float4 w0 = *(const float4*)&Wl[((KK) + 0) * 32 + tc4];                   \
    float4 w1 = *(const float4*)&Wl[((KK) + 1) * 32 + tc4];                   \
    float4 w2 = *(const float4*)&Wl[((KK) + 2) * 32 + tc4];                   \
    float4 w3 = *(const float4*)&Wl[((KK) + 3) * 32 + tc4];                   \
    f32x2 w0l = {w0.x, w0.y}, w0h = {w0.z, w0.w};                             \
    f32x2 w1l = {w1.x, w1.y}, w1h = {w1.z, w1.w};                             \
    f32x2 w2l = {w2.x, w2.y}, w2h = {w2.z, w2.w};                             \
    f32x2 w3l = {w3.x, w3.y}, w3h = {w3.z, w3.w};                             \
    _Pragma("unroll")                                                         \
    for (int r = 0; r < 4; ++r) {                                             \
      f32x2 s;                                                                \
      s = (f32x2){a[r].x, a[r].x};                                            \
      acc[r][0] = fma2(s, w0l, acc[r][0]); acc[r][1] = fma2(s, w0h, acc[r][1]);\
      s = (f32x2){a[r].y, a[r].y};                                            \
      acc[r][0] = fma2(s, w1l, acc[r][0]); acc[r][1] = fma2(s, w1h, acc[r][1]);\
      s = (f32x2){a[r].z, a[r].z};                                            \
      acc[r][0] = fma2(s, w2l, acc[r][0]); acc[r][1] = fma2(s, w2h, acc[r][1]);\
      s = (f32x2){a[r].w, a[r].w};                                            \
      acc[r][0] = fma2(s, w3l, acc[r][0]); acc[r][1] = fma2(s, w3h, acc[r][1]);\
    }                                                                         \
  }

#pragma unroll 2
  for (int k = 0; k < 252; k += 4) {
#pragma unroll
    for (int r = 0; r < 4; ++r) an[r] = *(const float4*)&xr[r * 256 + k + 4];
    GEMM_CHUNK(k)
#pragma unroll
    for (int r = 0; r < 4; ++r) a[r] = an[r];
  }
  GEMM_CHUNK(252)
#undef GEMM_CHUNK

  const float4 bb = *(const float4*)&bcol[tc4];
#pragma unroll
  for (int r = 0; r < 4; ++r) {
    float4 o;
    o.x = acc[r][0].x + bb.x; o.y = acc[r][0].y + bb.y;
    o.z = acc[r][1].x + bb.z; o.w = acc[r][1].y + bb.w;
    *(float4*)&Y[(size_t)(m0 + 4 * tr + r) * 256 + n0 + tc4] = o;
  }
}

// fused Q/K/V projection + dist row-sum pass:
//   z in {0,1,2}: gemm for q/k/v with on-the-fly weight packing
//   z == 3      : dist_stats (1024 blocks x 16 rows) - overlaps with gemms
__global__ __launch_bounds__(256, 4) void gemm_qkv_kernel(
    const float* __restrict__ q, const float* __restrict__ k,
    const float* __restrict__ v,
    const float* __restrict__ Wqd, const float* __restrict__ Wqa,
    const float* __restrict__ Wkd, const float* __restrict__ Wka,
    const float* __restrict__ Wvd, const float* __restrict__ Wva,
    const float* __restrict__ bqd, const float* __restrict__ bqa,
    const float* __restrict__ bkd, const float* __restrict__ bka,
    const float* __restrict__ bvd, const float* __restrict__ bva,
    const float* __restrict__ dist, const float* __restrict__ mask,
    float* __restrict__ dinv, float* __restrict__ Yb)
{
  const int z = blockIdx.z;
  if (z == 3) {
    // ---- dist stats: rows idx*16 .. idx*16+15, 4 rows per wave ----
    const int idx = blockIdx.y * 128 + blockIdx.x;     // 0..1023
    const int w = threadIdx.x >> 6, lane = threadIdx.x & 63;
#pragma unroll
    for (int rr = 0; rr < 4; ++rr) {
      const int row = idx * 16 + w * 4 + rr;
      const int b = row >> 10;
      const float* dr = dist + (size_t)row * 1024;
      const float* mrk = mask + b * 1024;
      float s = 0.f;
#pragma unroll
      for (int j = 0; j < 16; ++j) {
        int c = lane + 64 * j;
        s += __expf(dr[c] - 1e9f * mrk[c]);
      }
#pragma unroll
      for (int off = 32; off >= 1; off >>= 1) s += __shfl_xor(s, off);
      if (lane == 0) dinv[row] = 1.0f / s;
    }
    return;
  }
  const float* X  = (z == 0) ? q   : (z == 1) ? k   : v;
  const float* W0 = (z == 0) ? Wqd : (z == 1) ? Wkd : Wvd;
  const float* W1 = (z == 0) ? Wqa : (z == 1) ? Wka : Wva;
  const float* b0 = (z == 0) ? bqd : (z == 1) ? bkd : bvd;
  const float* b1 = (z == 0) ? bqa : (z == 1) ? bka : bva;
  const int n0 = blockIdx.y * 32;
  const float* Wcol = (n0 < 128) ? (W0 + n0) : (W1 + (n0 - 128));
  const float* bcol = (n0 < 128) ? (b0 + n0) : (b1 + (n0 - 128));
  gemm_body(X, Wcol, 128, bcol, Yb + (size_t)z * 4194304);
}

__global__ __launch_bounds__(256, 4) void gemm_out_kernel(
    const float* __restrict__ X, const float* __restrict__ Wo,
    const float* __restrict__ bo, float* __restrict__ Y)
{
  const int n0 = blockIdx.y * 32;
  gemm_body(X, Wo + n0, 256, bo + n0, Y);
}

// ---------------------------------------------------------------------------
// attn_fused v4: structure of v3 (4 waves x 4 q-rows, lane owns one column
// per 64-col tile, no-max softmax, register row-sums, wave-local epilogue)
// with the QK^T and PV inner loops converted to packed v_pk_fma_f32:
//   per 64-col tile: 8 ds_read_b128 + 64 pk-FMA (was 128 scalar FMA).
// LDS = 16x1024 (Ls) + 64x36 (KVs) = 74,752 B -> 2 blocks/CU.
// ---------------------------------------------------------------------------
__global__ __launch_bounds__(256, 2) void attn_fused_kernel(
    const float* __restrict__ Qc, const float* __restrict__ Kc,
    const float* __restrict__ Vc, const float* __restrict__ mask,
    const float* __restrict__ adj, const float* __restrict__ dist,
    const float* __restrict__ dinv,
    float* __restrict__ wout, float* __restrict__ conc)
{
  __shared__ float Ls[16384];      // [16][1024] e-values; epilogue: per-wave [64][64] swizzled
  __shared__ float KVs[64][36];    // K-tile, then V-tile staging (stride 36)
  const int t = threadIdx.x;
  const int bid = blockIdx.x;
  const int qb = bid & 63, h = (bid >> 6) & 7, b = bid >> 9;
  const int q0 = qb * 16;
  const int branch = h >> 2;
  const int boff = branch * 128 + (h & 3) * 32;
  const int wv = t >> 6, l = t & 63;     // wave id, lane id
  const int gr = q0 + 4 * wv;            // wave's first global q-row
  const int sr = t >> 2, sq = t & 3;     // staging: row sr (0..63), dim-quads sq, sq+4

  // ---- Q rows for this wave into packed registers (dead after phase 1) ----
  f32x2 Q2[4][16];
  const float* qbase = Qc + ((size_t)(b * 1024 + gr)) * 256 + boff;
#pragma unroll
  for (int r = 0; r < 4; ++r)
#pragma unroll
    for (int dq = 0; dq < 8; ++dq) {
      float4 a = *(const float4*)&qbase[(size_t)r * 256 + 4 * dq];
      Q2[r][2 * dq]     = (f32x2){a.x, a.y};
      Q2[r][2 * dq + 1] = (f32x2){a.z, a.w};
    }

  const float* kb = Kc + (size_t)(b * 1024) * 256 + boff;
  const float* mr = mask + b * 1024;

  // -------- Phase 1: e-values -> Ls, row-sums in registers --------
  float sp0 = 0.f, sp1 = 0.f, sp2 = 0.f, sp3 = 0.f;
  {
    float4 ka  = *(const float4*)&kb[(size_t)sr * 256 + 4 * sq];
    float4 kc2 = *(const float4*)&kb[(size_t)sr * 256 + 16 + 4 * sq];
    *(float4*)&KVs[sr][4 * sq] = ka;
    *(float4*)&KVs[sr][16 + 4 * sq] = kc2;
    __syncthreads();
  }
  float ngc = -1e9f * mr[l];
  for (int cc = 0; cc < 16; ++cc) {
    float4 nka, nkc2; float nng = 0.f;
    if (cc < 15) {
      const int cn0 = (cc + 1) * 64;
      nka  = *(const float4*)&kb[(size_t)(cn0 + sr) * 256 + 4 * sq];
      nkc2 = *(const float4*)&kb[(size_t)(cn0 + sr) * 256 + 16 + 4 * sq];
      nng = -1e9f * mr[cn0 + l];
    }
    const int c = cc * 64 + l;
    f32x2 t0 = {0.f, 0.f}, t1 = {0.f, 0.f}, t2 = {0.f, 0.f}, t3 = {0.f, 0.f};
#pragma unroll
    for (int dq = 0; dq < 8; ++dq) {
      float4 kv = *(const float4*)&KVs[l][4 * dq];
      f32x2 k01 = {kv.x, kv.y}, k23 = {kv.z, kv.w};
      t0 = fma2(Q2[0][2 * dq], k01, t0); t0 = fma2(Q2[0][2 * dq + 1], k23, t0);
      t1 = fma2(Q2[1][2 * dq], k01, t1); t1 = fma2(Q2[1][2 * dq + 1], k23, t1);
      t2 = fma2(Q2[2][2 * dq], k01, t2); t2 = fma2(Q2[2][2 * dq + 1], k23, t2);
      t3 = fma2(Q2[3][2 * dq], k01, t3); t3 = fma2(Q2[3][2 * dq + 1], k23, t3);
    }
    float e0 = __expf(fmaf(t0.x + t0.y, SCALE, ngc));
    float e1 = __expf(fmaf(t1.x + t1.y, SCALE, ngc));
    float e2 = __expf(fmaf(t2.x + t2.y, SCALE, ngc));
    float e3 = __expf(fmaf(t3.x + t3.y, SCALE, ngc));
    Ls[(4 * wv + 0) * 1024 + c] = e0;
    Ls[(4 * wv + 1) * 1024 + c] = e1;
    Ls[(4 * wv + 2) * 1024 + c] = e2;
    Ls[(4 * wv + 3) * 1024 + c] = e3;
    sp0 += e0; sp1 += e1; sp2 += e2; sp3 += e3;
    if (cc < 15) {
      __syncthreads();
      *(float4*)&KVs[sr][4 * sq] = nka;
      *(float4*)&KVs[sr][16 + 4 * sq] = nkc2;
      __syncthreads();
      ngc = nng;
    }
  }

  // -------- row-sum reduce (registers + shuffle only) --------
#pragma unroll
  for (int off = 32; off >= 1; off >>= 1) {
    sp0 += __shfl_xor(sp0, off);
    sp1 += __shfl_xor(sp1, off);
    sp2 += __shfl_xor(sp2, off);
    sp3 += __shfl_xor(sp3, off);
  }
  float inv[4] = {1.0f / sp0, 1.0f / sp1, 1.0f / sp2, 1.0f / sp3};

  // -------- Phase 2: reweight + w write + PV accumulate (packed) --------
  f32x2 o2[4][16];
#pragma unroll
  for (int r = 0; r < 4; ++r)
#pragma unroll
    for (int d = 0; d < 16; ++d) o2[r][d] = (f32x2){0.f, 0.f};

  const float* br_[4];
  float din[4];
  if (branch == 0) {
#pragma unroll
    for (int r = 0; r < 4; ++r) {
      din[r] = dinv[b * 1024 + gr + r];
      br_[r] = dist + (size_t)(b * 1024 + gr + r) * 1024;
    }
  } else {
#pragma unroll
    for (int r = 0; r < 4; ++r) {
      din[r] = 0.f;
      br_[r] = adj + (size_t)(b * 1024 + gr + r) * 1024;
    }
  }
  const float* vb = Vc + (size_t)(b * 1024) * 256 + boff;
  const size_t wr0 = ((size_t)(b * 8 + h) * 1024 + gr) * 1024;

  float fpre[4], ngc2;
  {
    float4 va  = *(const float4*)&vb[(size_t)sr * 256 + 4 * sq];
    float4 vc2 = *(const float4*)&vb[(size_t)sr * 256 + 16 + 4 * sq];
#pragma unroll
    for (int r = 0; r < 4; ++r) fpre[r] = br_[r][l];
    ngc2 = -1e9f * mr[l];
    __syncthreads();                     // all waves done reading last K tile
    *(float4*)&KVs[sr][4 * sq] = va;
    *(float4*)&KVs[sr][16 + 4 * sq] = vc2;
    __syncthreads();
  }
  for (int cc = 0; cc < 16; ++cc) {
    const int c = cc * 64 + l;
    float4 nva, nvc2; float nf[4]; float nng = 0.f;
    if (cc < 15) {
      const int cn0 = (cc + 1) * 64;
      nva  = *(const float4*)&vb[(size_t)(cn0 + sr) * 256 + 4 * sq];
      nvc2 = *(const float4*)&vb[(size_t)(cn0 + sr) * 256 + 16 + 4 * sq];
#pragma unroll
      for (int r = 0; r < 4; ++r) nf[r] = br_[r][cn0 + l];
      nng = -1e9f * mr[cn0 + l];
    }
    float w[4];
#pragma unroll
    for (int r = 0; r < 4; ++r) {
      float e = Ls[(4 * wv + r) * 1024 + c] * inv[r];
      float f;
      if (branch == 0) f = __expf(fpre[r] + ngc2) * din[r];
      else             f = fpre[r];
      w[r] = e * f;
      __builtin_nontemporal_store(w[r], &wout[wr0 + (size_t)r * 1024 + c]);
    }
    f32x2 wb0 = {w[0], w[0]}, wb1 = {w[1], w[1]};
    f32x2 wb2 = {w[2], w[2]}, wb3 = {w[3], w[3]};
#pragma unroll
    for (int dq = 0; dq < 8; ++dq) {
      float4 vv = *(const float4*)&KVs[l][4 * dq];
      f32x2 v01 = {vv.x, vv.y}, v23 = {vv.z, vv.w};
      o2[0][2 * dq]     = fma2(wb0, v01, o2[0][2 * dq]);
      o2[0][2 * dq + 1] = fma2(wb0, v23, o2[0][2 * dq + 1]);
      o2[1][2 * dq]     = fma2(wb1, v01, o2[1][2 * dq]);
      o2[1][2 * dq + 1] = fma2(wb1, v23, o2[1][2 * dq + 1]);
      o2[2][2 * dq]     = fma2(wb2, v01, o2[2][2 * dq]);
      o2[2][2 * dq + 1] = fma2(wb2, v23, o2[2][2 * dq + 1]);
      o2[3][2 * dq]     = fma2(wb3, v01, o2[3][2 * dq]);
      o2[3][2 * dq + 1] = fma2(wb3, v23, o2[3][2 * dq + 1]);
    }
    if (cc < 15) {
      __syncthreads();
      *(float4*)&KVs[sr][4 * sq] = nva;
      *(float4*)&KVs[sr][16 + 4 * sq] = nvc2;
      __syncthreads();
#pragma unroll
      for (int r = 0; r < 4; ++r) fpre[r] = nf[r];
      ngc2 = nng;
    }
  }

  // -------- Epilogue: wave-local swizzled transpose-reduce (no barriers) ----
  {
    float* Ws_ = &Ls[wv * 4096];
#pragma unroll
    for (int p = 0; p < 2; ++p) {
#pragma unroll
      for (int j = 0; j < 32; ++j) {
        const int r = j >> 4, d2 = j & 15;             // row 2p+r, dims 2d2..2d2+1
        const int slot = (j + l) & 31;
        *(f32x2*)&Ws_[l * 64 + 2 * slot] = o2[2 * p + r][d2];
      }
      const int rp = l >> 5, d = l & 31;
      const int jc = rp * 16 + (d >> 1);
      float a = 0.f;
#pragma unroll
      for (int ll = 0; ll < 64; ++ll)
        a += Ws_[ll * 64 + 2 * ((jc + ll) & 31) + (d & 1)];
      conc[((size_t)(b * 1024) + q0 + 4 * wv + 2 * p + rp) * 256 + boff + d] = a;
    }
  }
}

// ---------------------------------------------------------------------------
extern "C" void kernel_launch(void* const* d_in, const int* in_sizes, int n_in,
                              void* d_out, int out_size, void* d_ws, size_t ws_size,
                              hipStream_t stream)
{
  const float* v_ori = (const float*)d_in[0];
  const float* k_ori = (const float*)d_in[1];
  const float* q_ori = (const float*)d_in[2];
  const float* mask  = (const float*)d_in[3];
  const float* adj   = (const float*)d_in[4];
  const float* dist  = (const float*)d_in[5];
  const float* Wqd = (const float*)d_in[6];  const float* bqd = (const float*)d_in[7];
  const float* Wkd = (const float*)d_in[8];  const float* bkd = (const float*)d_in[9];
  const float* Wvd = (const float*)d_in[10]; const float* bvd = (const float*)d_in[11];
  const float* Wqa = (const float*)d_in[12]; const float* bqa = (const float*)d_in[13];
  const float* Wka = (const float*)d_in[14]; const float* bka = (const float*)d_in[15];
  const float* Wva = (const float*)d_in[16]; const float* bva = (const float*)d_in[17];
  const float* Wo  = (const float*)d_in[18]; const float* bo  = (const float*)d_in[19];

  float* out = (float*)d_out;
  float* ws  = (float*)d_ws;
  float* Qc    = ws;                  // 16384*256 (Qc,Kc,Vc contiguous)
  float* Kc    = Qc + 4194304;
  float* Vc    = Kc + 4194304;
  float* conc  = Vc + 4194304;        // 16384*256
  float* dinvb = conc + 4194304;      // 16384

  // z=0..2: Q/K/V projections (pack-on-stage); z=3: dist row-sums (overlapped)
  gemm_qkv_kernel<<<dim3(128, 8, 4), 256, 0, stream>>>(
      q_ori, k_ori, v_ori,
      Wqd, Wqa, Wkd, Wka, Wvd, Wva,
      bqd, bqa, bkd, bka, bvd, bva,
      dist, mask, dinvb, Qc);
  attn_fused_kernel<<<8192, 256, 0, stream>>>(Qc, Kc, Vc, mask, adj, dist,
                                              dinvb, out + OUTW, conc);
  gemm_out_kernel<<<dim3(128, 8), 256, 0, stream>>>(conc, Wo, bo, out);
}